// Round 3
// baseline (501.710 us; speedup 1.0000x reference)
//
#include <hip/hip_runtime.h>
#include <math.h>

#define N_EMB   1000000
#define D       64
#define E_PAIRS 65536
#define K_NEG   16
#define P_TOTAL (E_PAIRS * (K_NEG + 1))   /* 1114112 */
#define PPB     64                         /* pairs per block (LDS 26KB -> 6 blocks/CU) */
#define XS      200                        /* LDS X row stride in bf16 elems (400B): 16B-aligned, 2-way bank alias (free) */

typedef __attribute__((ext_vector_type(8))) short  short8;
typedef __attribute__((ext_vector_type(4))) float  float4v;

static __device__ __forceinline__ unsigned short f2bf(float f) {
    unsigned int x = __float_as_uint(f);
    unsigned int r = (x + 0x7fffu + ((x >> 16) & 1u)) >> 16;   // RNE
    return (unsigned short)r;
}

__global__ __launch_bounds__(256)
void prep_kernel(const float* __restrict__ W1, unsigned short* __restrict__ W1bf)
{
    int i = blockIdx.x * 256 + threadIdx.x;
    if (i < 64 * 192) W1bf[i] = f2bf(W1[i]);
}

__global__ __launch_bounds__(256, 6)
void score_kernel(const float* __restrict__ embeds,
                  const int*   __restrict__ pos,
                  const int*   __restrict__ neg,
                  const unsigned short* __restrict__ W1bf,
                  const float* __restrict__ b1,
                  const float* __restrict__ W2,
                  const float* __restrict__ b2,
                  float*       __restrict__ scores)
{
    __shared__ unsigned short X[PPB * XS];   // [u(64) | v(64) | u*v(64)] bf16 per pair, 25.6 KB
    __shared__ int uidx[PPB];
    __shared__ int vidx[PPB];

    const int t = threadIdx.x;
    const int pbase = blockIdx.x * PPB;

    // ---- stage pair indices (block-uniform pos/neg branch: E_PAIRS % PPB == 0) ----
    if (t < PPB) {
        int p = pbase + t;
        int ui, vi;
        if (p < E_PAIRS) {
            ui = pos[2 * p];
            vi = pos[2 * p + 1];
        } else {
            int q = p - E_PAIRS;
            ui = neg[2 * q];
            vi = neg[2 * q + 1];
        }
        uidx[t] = ui;
        vidx[t] = vi;
    }
    __syncthreads();

    // ---- gather: issue ALL 8 independent 16B loads first (MLP depth), then cvt+store ----
    // thread -> (pair pr = it*16 + t/16, segment seg = t&15); 16 lanes cover one 256B row.
    const int seg   = t & 15;
    const int rbase = t >> 4;           // 0..15
    float4 u4[4], v4[4];
    #pragma unroll
    for (int it = 0; it < 4; ++it) {
        int pr = it * 16 + rbase;
        u4[it] = *(const float4*)(embeds + (long long)uidx[pr] * D + seg * 4);
        v4[it] = *(const float4*)(embeds + (long long)vidx[pr] * D + seg * 4);
    }
    #pragma unroll
    for (int it = 0; it < 4; ++it) {
        int pr = it * 16 + rbase;
        float4 uu = u4[it], vv = v4[it];
        union { unsigned short s[4]; uint2 v; } pu, pv, pw;
        pu.s[0] = f2bf(uu.x); pu.s[1] = f2bf(uu.y); pu.s[2] = f2bf(uu.z); pu.s[3] = f2bf(uu.w);
        pv.s[0] = f2bf(vv.x); pv.s[1] = f2bf(vv.y); pv.s[2] = f2bf(vv.z); pv.s[3] = f2bf(vv.w);
        pw.s[0] = f2bf(uu.x * vv.x); pw.s[1] = f2bf(uu.y * vv.y);
        pw.s[2] = f2bf(uu.z * vv.z); pw.s[3] = f2bf(uu.w * vv.w);
        unsigned short* xp = X + pr * XS + seg * 4;
        *(uint2*)(xp)       = pu.v;
        *(uint2*)(xp + 64)  = pv.v;
        *(uint2*)(xp + 128) = pw.v;
    }
    __syncthreads();

    // ---- MFMA: each wave owns one 16-pair m-tile x 4 n-tiles, K=192 (6 steps) ----
    const int lane = t & 63;
    const int wave = t >> 6;
    const int c16  = lane & 15;
    const int quad = lane >> 4;
    const int wp0  = wave * 16;

    float4v acc[4];
    #pragma unroll
    for (int nt = 0; nt < 4; ++nt) acc[nt] = (float4v){0.f, 0.f, 0.f, 0.f};

    #pragma unroll
    for (int ks = 0; ks < 6; ++ks) {
        const int koff = ks * 32 + quad * 8;
        short8 a = *(const short8*)(X + (wp0 + c16) * XS + koff);
        short8 bfrag[4];
        #pragma unroll
        for (int nt = 0; nt < 4; ++nt)
            bfrag[nt] = *(const short8*)(W1bf + (nt * 16 + c16) * 192 + koff);
        #pragma unroll
        for (int nt = 0; nt < 4; ++nt)
            acc[nt] = __builtin_amdgcn_mfma_f32_16x16x32_bf16(a, bfrag[nt], acc[nt], 0, 0, 0);
    }

    // ---- epilogue: +b1, relu, dot W2, reduce over 16 n-lanes, sigmoid -> exp -> scores ----
    float b1v[4], w2v[4];
    #pragma unroll
    for (int nt = 0; nt < 4; ++nt) {
        b1v[nt] = b1[nt * 16 + c16];
        w2v[nt] = W2[nt * 16 + c16];
    }
    const float b2v = b2[0];

    #pragma unroll
    for (int reg = 0; reg < 4; ++reg) {
        float s = 0.f;
        #pragma unroll
        for (int nt = 0; nt < 4; ++nt) {
            float h = acc[nt][reg] + b1v[nt];
            s += (h > 0.f ? h : 0.f) * w2v[nt];
        }
        s += __shfl_xor(s, 1);
        s += __shfl_xor(s, 2);
        s += __shfl_xor(s, 4);
        s += __shfl_xor(s, 8);
        if (c16 == 0) {
            float sig = 1.f / (1.f + expf(-(s + b2v)));
            scores[pbase + wp0 + quad * 4 + reg] = expf(sig);
        }
    }
}

__global__ __launch_bounds__(256)
void reduce_kernel(const float* __restrict__ scores, float* __restrict__ partials)
{
    __shared__ float sdata[256];
    int e = blockIdx.x * 256 + threadIdx.x;    // e in [0, E_PAIRS)
    float pos_s = scores[e];
    const float* ns = scores + E_PAIRS + (size_t)e * K_NEG;
    float nsum = 0.f;
    #pragma unroll
    for (int c = 0; c < 4; ++c) {
        float4 v = *(const float4*)(ns + c * 4);
        nsum += v.x + v.y + v.z + v.w;
    }
    float term = pos_s / (pos_s + nsum + 1e-8f) + 1e-8f;
    sdata[threadIdx.x] = term;
    __syncthreads();
    for (int s = 128; s > 0; s >>= 1) {
        if (threadIdx.x < s) sdata[threadIdx.x] += sdata[threadIdx.x + s];
        __syncthreads();
    }
    if (threadIdx.x == 0) partials[blockIdx.x] = sdata[0];
}

__global__ __launch_bounds__(256)
void final_kernel(const float* __restrict__ partials, float* __restrict__ out)
{
    __shared__ float sdata[256];
    sdata[threadIdx.x] = partials[threadIdx.x];
    __syncthreads();
    for (int s = 128; s > 0; s >>= 1) {
        if (threadIdx.x < s) sdata[threadIdx.x] += sdata[threadIdx.x + s];
        __syncthreads();
    }
    if (threadIdx.x == 0) out[0] = -sdata[0];
}

extern "C" void kernel_launch(void* const* d_in, const int* in_sizes, int n_in,
                              void* d_out, int out_size, void* d_ws, size_t ws_size,
                              hipStream_t stream)
{
    const float* embeds = (const float*)d_in[0];
    const int*   pos    = (const int*)d_in[1];
    const int*   neg    = (const int*)d_in[2];
    const float* W1     = (const float*)d_in[3];
    const float* b1     = (const float*)d_in[4];
    const float* W2     = (const float*)d_in[5];
    const float* b2     = (const float*)d_in[6];
    float* out = (float*)d_out;

    float* scores   = (float*)d_ws;                           // P_TOTAL floats
    float* partials = scores + P_TOTAL;                       // 256 floats
    unsigned short* W1bf = (unsigned short*)(partials + 256); // 64*192 bf16 (16B-aligned)

    prep_kernel<<<48, 256, 0, stream>>>(W1, W1bf);
    score_kernel<<<P_TOTAL / PPB, 256, 0, stream>>>(embeds, pos, neg, W1bf, b1, W2, b2, scores);
    reduce_kernel<<<E_PAIRS / 256, 256, 0, stream>>>(scores, partials);
    final_kernel<<<1, 256, 0, stream>>>(partials, out);
}